// Round 2
// baseline (264.714 us; speedup 1.0000x reference)
//
#include <hip/hip_runtime.h>
#include <hip/hip_bf16.h>

#define U_ 2048
#define T_ 512
#define K_ 128
#define B_ 32
#define RHO_ 0.99f

typedef __attribute__((ext_vector_type(8))) short short8;
typedef __attribute__((ext_vector_type(4))) float f32x4;

__device__ __forceinline__ float fast_tanh(float x) {
  float e = __expf(2.0f * x);          // inf for large x -> returns +/-1 correctly
  return 1.0f - 2.0f / (e + 1.0f);
}

__device__ __forceinline__ unsigned short bf16_rne(float x) {
  unsigned int u = __float_as_uint(x);
  u += 0x7FFFu + ((u >> 16) & 1u);
  return (unsigned short)(u >> 16);
}

// ---------------- converts ----------------
// A [16384][128] fp32 -> Ab [16384][256] bf16 (k<128: hi, k>=128: lo residual)
__global__ __launch_bounds__(256) void convert_a_kernel(
    const float* __restrict__ A, unsigned short* __restrict__ Ab) {
  const int gi = blockIdx.x * 256 + threadIdx.x;
  const int m = gi >> 5;          // needs 2048 blocks
  const int kq = (gi & 31) << 2;
  const float4 v = *(const float4*)&A[(size_t)m * K_ + kq];
  ushort4 hi, lo;
  hi.x = bf16_rne(v.x); hi.y = bf16_rne(v.y); hi.z = bf16_rne(v.z); hi.w = bf16_rne(v.w);
  lo.x = bf16_rne(v.x - __uint_as_float((unsigned)hi.x << 16));
  lo.y = bf16_rne(v.y - __uint_as_float((unsigned)hi.y << 16));
  lo.z = bf16_rne(v.z - __uint_as_float((unsigned)hi.z << 16));
  lo.w = bf16_rne(v.w - __uint_as_float((unsigned)hi.w << 16));
  *(ushort4*)&Ab[(size_t)m * 256 + kq] = hi;
  *(ushort4*)&Ab[(size_t)m * 256 + 128 + kq] = lo;
}

// W [128][2048] fp32 -> Wbt [2048][256] bf16 transposed, duplicated along k
__global__ __launch_bounds__(256) void convert_w_kernel(
    const float* __restrict__ W, unsigned short* __restrict__ Wbt) {
  const int gi = blockIdx.x * 256 + threadIdx.x;   // 65536 threads
  const int kq = gi >> 11;        // 0..31
  const int n = gi & 2047;
  const int k = kq << 2;
  ushort4 w;
  w.x = bf16_rne(W[(size_t)(k + 0) * U_ + n]);
  w.y = bf16_rne(W[(size_t)(k + 1) * U_ + n]);
  w.z = bf16_rne(W[(size_t)(k + 2) * U_ + n]);
  w.w = bf16_rne(W[(size_t)(k + 3) * U_ + n]);
  *(ushort4*)&Wbt[(size_t)n * 256 + k] = w;
  *(ushort4*)&Wbt[(size_t)n * 256 + 128 + k] = w;
}

// ---------------- MFMA GEMM v5: LDS-staged full-line epilogue ----------------
// Same K-loop as v4 (XOR-swizzled unpadded LDS, 0 bank conflicts).  Epilogue
// stages each 64-row half of the 128x128 C tile in LDS (stride 132 to
// dodge bank conflicts), then streams it out with global_store_dwordx4 where
// each instruction covers 2 rows x 512B fully contiguous -> every 128B line
// is completed by one instruction.  Theory: kills the 2.8x HBM write
// amplification (374MB observed vs 134MB ideal) from the previous scalar
// 64B-fragment epilogue.
__global__ __launch_bounds__(256, 3) void mfma_gemm5_kernel(
    const unsigned short* __restrict__ Ab, const unsigned short* __restrict__ Wbt,
    const float* __restrict__ bias, float* __restrict__ out) {
  __shared__ union {
    struct { unsigned short a[128 * 64]; unsigned short b[128 * 64]; } ab;  // 32 KB
    float ct[64 * 132];                                                     // 33 KB
  } sm;
  unsigned short* const As = sm.ab.a;
  unsigned short* const Bs = sm.ab.b;
  const int tid = threadIdx.x;
  const int m0 = blockIdx.y << 7;
  const int n0 = blockIdx.x << 7;
  const int wave = tid >> 6;
  const int lane = tid & 63;
  const int r = lane & 15;        // row within 16x16 tile
  const int q = lane >> 4;        // quad
  const int mw = (wave >> 1) << 6;
  const int nw = (wave & 1) << 6;

  f32x4 acc[4][4] = {};

  // staging: wave w stages rows [32w, 32w+32) of A and B.
  const int rl8 = lane >> 3;                 // 0..7
  const int cg = lane & 7;                   // global chunk (coalesced)
  const int lchunk = cg ^ rl8;               // swizzled LDS chunk
  const int wrow0 = wave << 5;

  float4 av[4], bv4[4];
  #pragma unroll
  for (int j = 0; j < 4; ++j) {
    const int row = wrow0 + (j << 3) + rl8;
    av[j]  = *(const float4*)&Ab[((size_t)(m0 + row) << 8) + (cg << 3)];
    bv4[j] = *(const float4*)&Wbt[((size_t)(n0 + row) << 8) + (cg << 3)];
  }

  #pragma unroll
  for (int s = 0; s < 4; ++s) {
    if (s) __syncthreads();                  // LDS reads of step s-1 retired
    #pragma unroll
    for (int j = 0; j < 4; ++j) {
      const int row = wrow0 + (j << 3) + rl8;
      *(float4*)&As[(row << 6) + (lchunk << 3)] = av[j];
      *(float4*)&Bs[(row << 6) + (lchunk << 3)] = bv4[j];
    }
    __syncthreads();                         // staging visible

    if (s < 3) {                             // prefetch next K-step
      const int k0n = (s + 1) << 6;
      #pragma unroll
      for (int j = 0; j < 4; ++j) {
        const int row = wrow0 + (j << 3) + rl8;
        av[j]  = *(const float4*)&Ab[((size_t)(m0 + row) << 8) + k0n + (cg << 3)];
        bv4[j] = *(const float4*)&Wbt[((size_t)(n0 + row) << 8) + k0n + (cg << 3)];
      }
    }

    #pragma unroll
    for (int kk = 0; kk < 2; ++kk) {
      short8 af[4], bf[4];
      #pragma unroll
      for (int i = 0; i < 4; ++i) {
        const int row = mw + (i << 4) + r;
        af[i] = *(const short8*)&As[(row << 6) + ((((kk << 2) + q) ^ (row & 7)) << 3)];
      }
      #pragma unroll
      for (int j2 = 0; j2 < 4; ++j2) {
        const int row = nw + (j2 << 4) + r;
        bf[j2] = *(const short8*)&Bs[(row << 6) + ((((kk << 2) + q) ^ (row & 7)) << 3)];
      }
      #pragma unroll
      for (int i = 0; i < 4; ++i)
        #pragma unroll
        for (int j2 = 0; j2 < 4; ++j2)
          acc[i][j2] = __builtin_amdgcn_mfma_f32_16x16x32_bf16(af[i], bf[j2], acc[i][j2], 0, 0, 0);
    }
  }

  // ---- epilogue: LDS transpose to full-line stores ----
  // D layout: col (n) = lane&15, row (m) = q*4+reg.
  const int c4g = (tid & 31) << 2;           // col (floats) this thread stores
  const float4 bv = *(const float4*)&bias[n0 + c4g];
  #pragma unroll
  for (int half = 0; half < 2; ++half) {
    __syncthreads();                         // K-loop LDS reads / prev half done
    if ((wave >> 1) == half) {               // waves owning these 64 m-rows
      #pragma unroll
      for (int i = 0; i < 4; ++i)
        #pragma unroll
        for (int j = 0; j < 4; ++j) {
          const int col = nw + (j << 4) + r;
          #pragma unroll
          for (int reg = 0; reg < 4; ++reg) {
            const int row = (i << 4) + (q << 2) + reg;   // 0..63 local m
            sm.ct[row * 132 + col] = acc[i][j][reg];
          }
        }
    }
    __syncthreads();
    const int rowb = tid >> 5;               // 0..7
    #pragma unroll
    for (int it = 0; it < 8; ++it) {
      const int row = (it << 3) + rowb;      // 0..63
      const float4 v = *(const float4*)&sm.ct[row * 132 + c4g];
      float4 o;
      o.x = v.x + bv.x; o.y = v.y + bv.y; o.z = v.z + bv.z; o.w = v.w + bv.w;
      *(float4*)&out[((size_t)(m0 + (half << 6) + row) << 11) + n0 + c4g] = o;
    }
  }
}

// ---------------- in-place diagonal scan (depth-16 prefetch) ----------------
// buf holds u+bias in natural [B*T][U] layout; chain c of batch b computes
// h_t = tanh(u[t][(c+t)%U] + 0.99*h_{t-1}) in place.  Occupancy is capped at
// 4 waves/CU by chain count (65536), so latency hiding must come from ILP:
// 16 loads in flight per thread (was 8) -> 16KB/CU outstanding.
__global__ __launch_bounds__(256) void ring_scan_kernel(
    float* __restrict__ buf, const float* __restrict__ h0) {
  const int b = blockIdx.y;
  const int c = (blockIdx.x << 8) + threadIdx.x;
  float* const base = buf + (size_t)b * (T_ * U_);
  float h = h0[((size_t)b << 11) + ((c + U_ - 1) & (U_ - 1))];
  float wA[16], wB[16];
  #pragma unroll
  for (int j = 0; j < 16; ++j)
    wA[j] = base[((size_t)j << 11) + ((c + j) & (U_ - 1))];
  for (int t0 = 0; t0 < T_; t0 += 32) {
    #pragma unroll
    for (int j = 0; j < 16; ++j) {
      const int t = t0 + 16 + j;
      wB[j] = base[((size_t)t << 11) + ((c + t) & (U_ - 1))];
    }
    #pragma unroll
    for (int j = 0; j < 16; ++j) {
      const int t = t0 + j;
      h = fast_tanh(fmaf(RHO_, h, wA[j]));
      base[((size_t)t << 11) + ((c + t) & (U_ - 1))] = h;
    }
    if (t0 + 32 < T_) {
      #pragma unroll
      for (int j = 0; j < 16; ++j) {
        const int t = t0 + 32 + j;
        wA[j] = base[((size_t)t << 11) + ((c + t) & (U_ - 1))];
      }
    }
    #pragma unroll
    for (int j = 0; j < 16; ++j) {
      const int t = t0 + 16 + j;
      h = fast_tanh(fmaf(RHO_, h, wB[j]));
      base[((size_t)t << 11) + ((c + t) & (U_ - 1))] = h;
    }
  }
}

// ---------------- fallback path (R1, proven correct) ----------------
__global__ __launch_bounds__(256, 4) void gemm_bias_kernel(
    const float* __restrict__ A, const float* __restrict__ W,
    const float* __restrict__ bias, float* __restrict__ out) {
  __shared__ float Asf[64][68];
  __shared__ float Bsf[64][64];
  const int tid = threadIdx.x;
  const int m0 = blockIdx.y << 6;
  const int n0 = blockIdx.x << 6;
  const int tx = tid & 15;
  const int ty = tid >> 4;
  float acc[4][4] = {};
  #pragma unroll
  for (int kb = 0; kb < 2; ++kb) {
    if (kb) __syncthreads();
    {
      const int c4 = tid & 15;
      const int r0 = tid >> 4;
      #pragma unroll
      for (int rr = 0; rr < 4; ++rr) {
        const int r = r0 + (rr << 4);
        const float4 v = *(const float4*)(A + (size_t)(m0 + r) * K_ + (kb << 6) + (c4 << 2));
        Asf[(c4 << 2) + 0][r] = v.x;
        Asf[(c4 << 2) + 1][r] = v.y;
        Asf[(c4 << 2) + 2][r] = v.z;
        Asf[(c4 << 2) + 3][r] = v.w;
      }
    }
    {
      const int c4 = tid & 15;
      const int r0 = tid >> 4;
      #pragma unroll
      for (int rr = 0; rr < 4; ++rr) {
        const int k = r0 + (rr << 4);
        *(float4*)&Bsf[k][c4 << 2] =
            *(const float4*)(W + (size_t)((kb << 6) + k) * U_ + n0 + (c4 << 2));
      }
    }
    __syncthreads();
    #pragma unroll 16
    for (int k = 0; k < 64; ++k) {
      const float4 a = *(const float4*)&Asf[k][ty << 2];
      const float4 b = *(const float4*)&Bsf[k][tx << 2];
      acc[0][0] = fmaf(a.x, b.x, acc[0][0]); acc[0][1] = fmaf(a.x, b.y, acc[0][1]);
      acc[0][2] = fmaf(a.x, b.z, acc[0][2]); acc[0][3] = fmaf(a.x, b.w, acc[0][3]);
      acc[1][0] = fmaf(a.y, b.x, acc[1][0]); acc[1][1] = fmaf(a.y, b.y, acc[1][1]);
      acc[1][2] = fmaf(a.y, b.z, acc[1][2]); acc[1][3] = fmaf(a.y, b.w, acc[1][3]);
      acc[2][0] = fmaf(a.z, b.x, acc[2][0]); acc[2][1] = fmaf(a.z, b.y, acc[2][1]);
      acc[2][2] = fmaf(a.z, b.z, acc[2][2]); acc[2][3] = fmaf(a.z, b.w, acc[2][3]);
      acc[3][0] = fmaf(a.w, b.x, acc[3][0]); acc[3][1] = fmaf(a.w, b.y, acc[3][1]);
      acc[3][2] = fmaf(a.w, b.z, acc[3][2]); acc[3][3] = fmaf(a.w, b.w, acc[3][3]);
    }
  }
  const float4 bv = *(const float4*)(bias + n0 + (tx << 2));
  #pragma unroll
  for (int i = 0; i < 4; ++i) {
    float4 o;
    o.x = acc[i][0] + bv.x; o.y = acc[i][1] + bv.y;
    o.z = acc[i][2] + bv.z; o.w = acc[i][3] + bv.w;
    *(float4*)(out + (size_t)(m0 + (ty << 2) + i) * U_ + n0 + (tx << 2)) = o;
  }
}

extern "C" void kernel_launch(void* const* d_in, const int* in_sizes, int n_in,
                              void* d_out, int out_size, void* d_ws, size_t ws_size,
                              hipStream_t stream) {
  const float* A    = (const float*)d_in[0];   // inputs [B,T,D_IN]
  const float* h0   = (const float*)d_in[1];   // [B,U]
  const float* W    = (const float*)d_in[2];   // kernel [D_IN,U]
  const float* bias = (const float*)d_in[3];   // [U]
  float* out = (float*)d_out;                  // [B,T,U]

  const size_t AB_BYTES = (size_t)B_ * T_ * 256 * 2;         // 8,388,608
  const size_t WB_BYTES = (size_t)U_ * 256 * 2;              // 1,048,576
  const size_t NEEDED = AB_BYTES + WB_BYTES;

  if (ws_size >= NEEDED) {
    unsigned short* Ab  = (unsigned short*)d_ws;
    unsigned short* Wbt = (unsigned short*)((char*)d_ws + AB_BYTES);

    convert_a_kernel<<<2048, 256, 0, stream>>>(A, Ab);   // 16384 rows * 32 quads
    convert_w_kernel<<<256, 256, 0, stream>>>(W, Wbt);
    dim3 gg(U_ / 128, (B_ * T_) / 128);   // (16, 128)
    mfma_gemm5_kernel<<<gg, 256, 0, stream>>>(Ab, Wbt, bias, out);
  } else {
    dim3 gemm_grid(U_ / 64, (B_ * T_) / 64);
    gemm_bias_kernel<<<gemm_grid, 256, 0, stream>>>(A, W, bias, out);
  }
  dim3 scan_grid(U_ / 256, B_);           // (8, 32)
  ring_scan_kernel<<<scan_grid, 256, 0, stream>>>(out, h0);
}

// Round 3
// 261.081 us; speedup vs baseline: 1.0139x; 1.0139x over previous
//
#include <hip/hip_runtime.h>
#include <hip/hip_bf16.h>

#define U_ 2048
#define T_ 512
#define K_ 128
#define B_ 32
#define RHO_ 0.99f

typedef __attribute__((ext_vector_type(8))) short short8;
typedef __attribute__((ext_vector_type(4))) float f32x4;

__device__ __forceinline__ float fast_tanh(float x) {
  float e = __expf(2.0f * x);          // inf for large x -> returns +/-1 correctly
  return 1.0f - 2.0f / (e + 1.0f);
}

__device__ __forceinline__ unsigned short bf16_rne(float x) {
  unsigned int u = __float_as_uint(x);
  u += 0x7FFFu + ((u >> 16) & 1u);
  return (unsigned short)(u >> 16);
}

// ---------------- converts ----------------
// A [16384][128] fp32 -> Ab [16384][256] bf16 (k<128: hi, k>=128: lo residual)
__global__ __launch_bounds__(256) void convert_a_kernel(
    const float* __restrict__ A, unsigned short* __restrict__ Ab) {
  const int gi = blockIdx.x * 256 + threadIdx.x;
  const int m = gi >> 5;          // needs 2048 blocks
  const int kq = (gi & 31) << 2;
  const float4 v = *(const float4*)&A[(size_t)m * K_ + kq];
  ushort4 hi, lo;
  hi.x = bf16_rne(v.x); hi.y = bf16_rne(v.y); hi.z = bf16_rne(v.z); hi.w = bf16_rne(v.w);
  lo.x = bf16_rne(v.x - __uint_as_float((unsigned)hi.x << 16));
  lo.y = bf16_rne(v.y - __uint_as_float((unsigned)hi.y << 16));
  lo.z = bf16_rne(v.z - __uint_as_float((unsigned)hi.z << 16));
  lo.w = bf16_rne(v.w - __uint_as_float((unsigned)hi.w << 16));
  *(ushort4*)&Ab[(size_t)m * 256 + kq] = hi;
  *(ushort4*)&Ab[(size_t)m * 256 + 128 + kq] = lo;
}

// W [128][2048] fp32 -> Wbt [2048][256] bf16 transposed, duplicated along k
__global__ __launch_bounds__(256) void convert_w_kernel(
    const float* __restrict__ W, unsigned short* __restrict__ Wbt) {
  const int gi = blockIdx.x * 256 + threadIdx.x;   // 65536 threads
  const int kq = gi >> 11;        // 0..31
  const int n = gi & 2047;
  const int k = kq << 2;
  ushort4 w;
  w.x = bf16_rne(W[(size_t)(k + 0) * U_ + n]);
  w.y = bf16_rne(W[(size_t)(k + 1) * U_ + n]);
  w.z = bf16_rne(W[(size_t)(k + 2) * U_ + n]);
  w.w = bf16_rne(W[(size_t)(k + 3) * U_ + n]);
  *(ushort4*)&Wbt[(size_t)n * 256 + k] = w;
  *(ushort4*)&Wbt[(size_t)n * 256 + 128 + k] = w;
}

// ---------------- MFMA GEMM v6: no-LDS, direct-from-L2 fragments ----------------
// K=256 (hi/lo split) is tiny and both operand panels are L2-resident
// (A panel 64KB reused 16x, Wbt 1MB reused 128x).  The 16x16x32 bf16 MFMA
// A/B fragment for lane (r,q) is 8 CONSECUTIVE k-elements at
// row*256 + ks*32 + q*8 -> one 16B global load; per wave each fragment load
// covers 16 rows x 64B fully-utilized segments (perfect request efficiency).
// So: no LDS, no barriers, no staging registers (kills spill pressure).
// All output stores are nontemporal: the 134MB write stream must not evict
// the hot panels from L2 (theory for the 80MB excess FETCH of v4/v5).
__global__ __launch_bounds__(256, 3) void mfma_gemm6_kernel(
    const unsigned short* __restrict__ Ab, const unsigned short* __restrict__ Wbt,
    const float* __restrict__ bias, float* __restrict__ out) {
  const int tid = threadIdx.x;
  const int m0 = blockIdx.y << 7;
  const int n0 = blockIdx.x << 7;
  const int wave = tid >> 6;
  const int lane = tid & 63;
  const int r = lane & 15;        // row within 16x16 tile
  const int q = lane >> 4;        // quad
  const int mw = (wave >> 1) << 6;
  const int nw = (wave & 1) << 6;

  f32x4 acc[4][4] = {};

  // per-lane fragment base pointers (k-offset q*8 elements)
  const unsigned short* const aB = Ab + (((size_t)(m0 + mw + r)) << 8) + (q << 3);
  const unsigned short* const bB = Wbt + (((size_t)(n0 + nw + r)) << 8) + (q << 3);

  #pragma unroll
  for (int ks = 0; ks < 8; ++ks) {          // 8 k-steps of 32 (256 total)
    short8 af[4], bf[4];
    #pragma unroll
    for (int i = 0; i < 4; ++i)
      af[i] = *(const short8*)(aB + ((size_t)(i << 4) << 8) + (ks << 5));
    #pragma unroll
    for (int j = 0; j < 4; ++j)
      bf[j] = *(const short8*)(bB + ((size_t)(j << 4) << 8) + (ks << 5));
    #pragma unroll
    for (int i = 0; i < 4; ++i)
      #pragma unroll
      for (int j = 0; j < 4; ++j)
        acc[i][j] = __builtin_amdgcn_mfma_f32_16x16x32_bf16(af[i], bf[j], acc[i][j], 0, 0, 0);
  }

  // epilogue: +bias, direct nontemporal stores
  // D layout: col (n) = lane&15, row (m) = q*4+reg.  Per (i,j,reg) a wave
  // covers 16 consecutive floats x 4 rows = four fully-covered 64B segments.
  #pragma unroll
  for (int j = 0; j < 4; ++j) {
    const int n = n0 + nw + (j << 4) + r;
    const float bv = bias[n];
    #pragma unroll
    for (int i = 0; i < 4; ++i) {
      const int mb = m0 + mw + (i << 4) + (q << 2);
      #pragma unroll
      for (int reg = 0; reg < 4; ++reg)
        __builtin_nontemporal_store(acc[i][j][reg] + bv,
                                    &out[((size_t)(mb + reg) << 11) + n]);
    }
  }
}

// ---------------- in-place diagonal scan (depth-16 prefetch, nt stores) -------
// buf holds u+bias in natural [B*T][U] layout; chain c of batch b computes
// h_t = tanh(u[t][(c+t)%U] + 0.99*h_{t-1}) in place.  Each location is read
// once (u) then overwritten once (h) and never re-read -> nontemporal stores.
__global__ __launch_bounds__(256) void ring_scan_kernel(
    float* __restrict__ buf, const float* __restrict__ h0) {
  const int b = blockIdx.y;
  const int c = (blockIdx.x << 8) + threadIdx.x;
  float* const base = buf + (size_t)b * (T_ * U_);
  float h = h0[((size_t)b << 11) + ((c + U_ - 1) & (U_ - 1))];
  float wA[16], wB[16];
  #pragma unroll
  for (int j = 0; j < 16; ++j)
    wA[j] = base[((size_t)j << 11) + ((c + j) & (U_ - 1))];
  for (int t0 = 0; t0 < T_; t0 += 32) {
    #pragma unroll
    for (int j = 0; j < 16; ++j) {
      const int t = t0 + 16 + j;
      wB[j] = base[((size_t)t << 11) + ((c + t) & (U_ - 1))];
    }
    #pragma unroll
    for (int j = 0; j < 16; ++j) {
      const int t = t0 + j;
      h = fast_tanh(fmaf(RHO_, h, wA[j]));
      __builtin_nontemporal_store(h, &base[((size_t)t << 11) + ((c + t) & (U_ - 1))]);
    }
    if (t0 + 32 < T_) {
      #pragma unroll
      for (int j = 0; j < 16; ++j) {
        const int t = t0 + 32 + j;
        wA[j] = base[((size_t)t << 11) + ((c + t) & (U_ - 1))];
      }
    }
    #pragma unroll
    for (int j = 0; j < 16; ++j) {
      const int t = t0 + 8 + 8 + j;
      h = fast_tanh(fmaf(RHO_, h, wB[j]));
      __builtin_nontemporal_store(h, &base[((size_t)t << 11) + ((c + t) & (U_ - 1))]);
    }
  }
}

// ---------------- fallback path (R1, proven correct) ----------------
__global__ __launch_bounds__(256, 4) void gemm_bias_kernel(
    const float* __restrict__ A, const float* __restrict__ W,
    const float* __restrict__ bias, float* __restrict__ out) {
  __shared__ float Asf[64][68];
  __shared__ float Bsf[64][64];
  const int tid = threadIdx.x;
  const int m0 = blockIdx.y << 6;
  const int n0 = blockIdx.x << 6;
  const int tx = tid & 15;
  const int ty = tid >> 4;
  float acc[4][4] = {};
  #pragma unroll
  for (int kb = 0; kb < 2; ++kb) {
    if (kb) __syncthreads();
    {
      const int c4 = tid & 15;
      const int r0 = tid >> 4;
      #pragma unroll
      for (int rr = 0; rr < 4; ++rr) {
        const int r = r0 + (rr << 4);
        const float4 v = *(const float4*)(A + (size_t)(m0 + r) * K_ + (kb << 6) + (c4 << 2));
        Asf[(c4 << 2) + 0][r] = v.x;
        Asf[(c4 << 2) + 1][r] = v.y;
        Asf[(c4 << 2) + 2][r] = v.z;
        Asf[(c4 << 2) + 3][r] = v.w;
      }
    }
    {
      const int c4 = tid & 15;
      const int r0 = tid >> 4;
      #pragma unroll
      for (int rr = 0; rr < 4; ++rr) {
        const int k = r0 + (rr << 4);
        *(float4*)&Bsf[k][c4 << 2] =
            *(const float4*)(W + (size_t)((kb << 6) + k) * U_ + n0 + (c4 << 2));
      }
    }
    __syncthreads();
    #pragma unroll 16
    for (int k = 0; k < 64; ++k) {
      const float4 a = *(const float4*)&Asf[k][ty << 2];
      const float4 b = *(const float4*)&Bsf[k][tx << 2];
      acc[0][0] = fmaf(a.x, b.x, acc[0][0]); acc[0][1] = fmaf(a.x, b.y, acc[0][1]);
      acc[0][2] = fmaf(a.x, b.z, acc[0][2]); acc[0][3] = fmaf(a.x, b.w, acc[0][3]);
      acc[1][0] = fmaf(a.y, b.x, acc[1][0]); acc[1][1] = fmaf(a.y, b.y, acc[1][1]);
      acc[1][2] = fmaf(a.y, b.z, acc[1][2]); acc[1][3] = fmaf(a.y, b.w, acc[1][3]);
      acc[2][0] = fmaf(a.z, b.x, acc[2][0]); acc[2][1] = fmaf(a.z, b.y, acc[2][1]);
      acc[2][2] = fmaf(a.z, b.z, acc[2][2]); acc[2][3] = fmaf(a.z, b.w, acc[2][3]);
      acc[3][0] = fmaf(a.w, b.x, acc[3][0]); acc[3][1] = fmaf(a.w, b.y, acc[3][1]);
      acc[3][2] = fmaf(a.w, b.z, acc[3][2]); acc[3][3] = fmaf(a.w, b.w, acc[3][3]);
    }
  }
  const float4 bv = *(const float4*)(bias + n0 + (tx << 2));
  #pragma unroll
  for (int i = 0; i < 4; ++i) {
    float4 o;
    o.x = acc[i][0] + bv.x; o.y = acc[i][1] + bv.y;
    o.z = acc[i][2] + bv.z; o.w = acc[i][3] + bv.w;
    *(float4*)(out + (size_t)(m0 + (ty << 2) + i) * U_ + n0 + (tx << 2)) = o;
  }
}

extern "C" void kernel_launch(void* const* d_in, const int* in_sizes, int n_in,
                              void* d_out, int out_size, void* d_ws, size_t ws_size,
                              hipStream_t stream) {
  const float* A    = (const float*)d_in[0];   // inputs [B,T,D_IN]
  const float* h0   = (const float*)d_in[1];   // [B,U]
  const float* W    = (const float*)d_in[2];   // kernel [D_IN,U]
  const float* bias = (const float*)d_in[3];   // [U]
  float* out = (float*)d_out;                  // [B,T,U]

  const size_t AB_BYTES = (size_t)B_ * T_ * 256 * 2;         // 8,388,608
  const size_t WB_BYTES = (size_t)U_ * 256 * 2;              // 1,048,576
  const size_t NEEDED = AB_BYTES + WB_BYTES;

  if (ws_size >= NEEDED) {
    unsigned short* Ab  = (unsigned short*)d_ws;
    unsigned short* Wbt = (unsigned short*)((char*)d_ws + AB_BYTES);

    convert_a_kernel<<<2048, 256, 0, stream>>>(A, Ab);   // 16384 rows * 32 quads
    convert_w_kernel<<<256, 256, 0, stream>>>(W, Wbt);
    dim3 gg(U_ / 128, (B_ * T_) / 128);   // (16, 128)
    mfma_gemm6_kernel<<<gg, 256, 0, stream>>>(Ab, Wbt, bias, out);
  } else {
    dim3 gemm_grid(U_ / 64, (B_ * T_) / 64);
    gemm_bias_kernel<<<gemm_grid, 256, 0, stream>>>(A, W, bias, out);
  }
  dim3 scan_grid(U_ / 256, B_);           // (8, 32)
  ring_scan_kernel<<<scan_grid, 256, 0, stream>>>(out, h0);
}

// Round 4
// 258.461 us; speedup vs baseline: 1.0242x; 1.0101x over previous
//
#include <hip/hip_runtime.h>
#include <hip/hip_bf16.h>

#define U_ 2048
#define T_ 512
#define K_ 128
#define B_ 32
#define RHO_ 0.99f

typedef __attribute__((ext_vector_type(8))) short short8;
typedef __attribute__((ext_vector_type(4))) float f32x4;

__device__ __forceinline__ float fast_tanh(float x) {
  float e = __expf(2.0f * x);          // inf for large x -> returns +/-1 correctly
  return 1.0f - 2.0f / (e + 1.0f);
}

__device__ __forceinline__ unsigned short bf16_rne(float x) {
  unsigned int u = __float_as_uint(x);
  u += 0x7FFFu + ((u >> 16) & 1u);
  return (unsigned short)(u >> 16);
}

// ---------------- converts ----------------
// A [16384][128] fp32 -> Ab [16384][256] bf16 (k<128: hi, k>=128: lo residual)
__global__ __launch_bounds__(256) void convert_a_kernel(
    const float* __restrict__ A, unsigned short* __restrict__ Ab) {
  const int gi = blockIdx.x * 256 + threadIdx.x;
  const int m = gi >> 5;          // needs 2048 blocks
  const int kq = (gi & 31) << 2;
  const float4 v = *(const float4*)&A[(size_t)m * K_ + kq];
  ushort4 hi, lo;
  hi.x = bf16_rne(v.x); hi.y = bf16_rne(v.y); hi.z = bf16_rne(v.z); hi.w = bf16_rne(v.w);
  lo.x = bf16_rne(v.x - __uint_as_float((unsigned)hi.x << 16));
  lo.y = bf16_rne(v.y - __uint_as_float((unsigned)hi.y << 16));
  lo.z = bf16_rne(v.z - __uint_as_float((unsigned)hi.z << 16));
  lo.w = bf16_rne(v.w - __uint_as_float((unsigned)hi.w << 16));
  *(ushort4*)&Ab[(size_t)m * 256 + kq] = hi;
  *(ushort4*)&Ab[(size_t)m * 256 + 128 + kq] = lo;
}

// W [128][2048] fp32 -> Wbt [2048][256] bf16 transposed, duplicated along k.
// (W entries are +/-1 -> exactly bf16; duplication matches Ab's hi/lo K=256.)
__global__ __launch_bounds__(256) void convert_w_kernel(
    const float* __restrict__ W, unsigned short* __restrict__ Wbt) {
  const int gi = blockIdx.x * 256 + threadIdx.x;   // 65536 threads
  const int kq = gi >> 11;        // 0..31
  const int n = gi & 2047;
  const int k = kq << 2;
  ushort4 w;
  w.x = bf16_rne(W[(size_t)(k + 0) * U_ + n]);
  w.y = bf16_rne(W[(size_t)(k + 1) * U_ + n]);
  w.z = bf16_rne(W[(size_t)(k + 2) * U_ + n]);
  w.w = bf16_rne(W[(size_t)(k + 3) * U_ + n]);
  *(ushort4*)&Wbt[(size_t)n * 256 + k] = w;
  *(ushort4*)&Wbt[(size_t)n * 256 + 128 + k] = w;
}

// ---------------- v7: fused GEMM + diagonal scan ----------------
// One block per (256-chain group, batch).  Per 16-step t-tile:
//   1. MFMA the u-tile [16 t-rows x 272 cols] from prefetched A/W fragments
//      (16x16x32 bf16, hi/lo split on A; W frags ks0..3 reused for lo half).
//   2. barrier; write u+bias into LDS (stride 273 to spread banks);
//      issue next t-tile's fragment loads (latency hides under scan phase).
//   3. barrier; each thread reads its 16 diagonal u values and runs the
//      sequential tanh recurrence, nontemporal-storing h straight to out.
// Deletes the 134MB u-write + 134MB u-read of the split version.
// Fragment scheme identical to the proven v6 GEMM (D: col=lane&15, row=q*4+reg).
__global__ __launch_bounds__(256) void fused_gemm_scan_kernel(
    const unsigned short* __restrict__ Ab, const unsigned short* __restrict__ Wbt,
    const float* __restrict__ bias, const float* __restrict__ h0,
    float* __restrict__ out) {
  __shared__ float u_lds[16 * 273];    // 17472 B
  __shared__ float bias_lds[U_];       //  8192 B
  const int tid = threadIdx.x;
  const int b = blockIdx.y;
  const int c0 = blockIdx.x << 8;
  const int c = c0 + tid;              // this thread's chain
  const int wave = tid >> 6;
  const int lane = tid & 63;
  const int r = lane & 15;
  const int q = lane >> 4;
  const int koff = q << 3;             // k-offset within 32-step (8 elems)

  #pragma unroll
  for (int i = 0; i < 8; ++i)
    bias_lds[(i << 8) + tid] = bias[(i << 8) + tid];

  float h = h0[((size_t)b << 11) + ((c + U_ - 1) & (U_ - 1))];

  const unsigned short* const aBase = Ab + (((size_t)b * T_) << 8);

  // fragment registers (rolling across t-tiles)
  short8 af[8];        // A rows t0+r, 8 k-steps (hi: 0-3, lo: 4-7)
  short8 bf[5][4];     // this wave's col-tiles, 4 distinct k-steps (dup'd halves)

  // prologue: load fragments for t0 = 0
  #pragma unroll
  for (int ks = 0; ks < 8; ++ks)
    af[ks] = *(const short8*)(aBase + (((size_t)r) << 8) + (ks << 5) + koff);
  #pragma unroll
  for (int jj = 0; jj < 5; ++jj) {
    const int j = (jj < 4) ? (wave + (jj << 2)) : 16;
    if (jj < 4 || wave == 0) {
      const int n = (c0 + (j << 4) + r) & (U_ - 1);
      #pragma unroll
      for (int ks = 0; ks < 4; ++ks)
        bf[jj][ks] = *(const short8*)(Wbt + (((size_t)n) << 8) + (ks << 5) + koff);
    }
  }
  __syncthreads();                     // bias_lds ready

  for (int t0 = 0; t0 < T_; t0 += 16) {
    // ---- MFMA phase: u-tile [16 x 272], 17 col-tiles over 4 waves ----
    f32x4 acc[5] = {};
    #pragma unroll
    for (int ks = 0; ks < 8; ++ks)
      #pragma unroll
      for (int jj = 0; jj < 5; ++jj)
        if (jj < 4 || wave == 0)
          acc[jj] = __builtin_amdgcn_mfma_f32_16x16x32_bf16(
              af[ks], bf[jj][ks & 3], acc[jj], 0, 0, 0);

    __syncthreads();                   // prev scan's u_lds reads retired

    // ---- write u + bias to LDS ----
    #pragma unroll
    for (int jj = 0; jj < 5; ++jj) {
      const int j = (jj < 4) ? (wave + (jj << 2)) : 16;
      if (jj < 4 || wave == 0) {
        const float bv = bias_lds[(c0 + t0 + (j << 4) + r) & (U_ - 1)];
        #pragma unroll
        for (int reg = 0; reg < 4; ++reg)
          u_lds[((q << 2) + reg) * 273 + (j << 4) + r] = acc[jj][reg] + bv;
      }
    }

    // ---- prefetch next t-tile fragments (completes during scan phase) ----
    if (t0 + 16 < T_) {
      #pragma unroll
      for (int ks = 0; ks < 8; ++ks)
        af[ks] = *(const short8*)(aBase + (((size_t)(t0 + 16 + r)) << 8) + (ks << 5) + koff);
      #pragma unroll
      for (int jj = 0; jj < 5; ++jj) {
        const int j = (jj < 4) ? (wave + (jj << 2)) : 16;
        if (jj < 4 || wave == 0) {
          const int n = (c0 + t0 + 16 + (j << 4) + r) & (U_ - 1);
          #pragma unroll
          for (int ks = 0; ks < 4; ++ks)
            bf[jj][ks] = *(const short8*)(Wbt + (((size_t)n) << 8) + (ks << 5) + koff);
        }
      }
    }

    __syncthreads();                   // u_lds visible

    // ---- scan phase: 16 sequential steps on the diagonal ----
    float uv[16];
    #pragma unroll
    for (int tt = 0; tt < 16; ++tt)
      uv[tt] = u_lds[tt * 273 + tid + tt];
    float* const orow = out + (((size_t)(b * T_ + t0)) << 11);
    #pragma unroll
    for (int tt = 0; tt < 16; ++tt) {
      h = fast_tanh(fmaf(RHO_, h, uv[tt]));
      __builtin_nontemporal_store(
          h, &orow[((size_t)tt << 11) + ((c + t0 + tt) & (U_ - 1))]);
    }
  }
}

// ---------------- fallback path (R1, proven correct) ----------------
__global__ __launch_bounds__(256) void ring_scan_kernel(
    float* __restrict__ buf, const float* __restrict__ h0) {
  const int b = blockIdx.y;
  const int c = (blockIdx.x << 8) + threadIdx.x;
  float* const base = buf + (size_t)b * (T_ * U_);
  float h = h0[((size_t)b << 11) + ((c + U_ - 1) & (U_ - 1))];
  float wA[8], wB[8];
  #pragma unroll
  for (int j = 0; j < 8; ++j)
    wA[j] = base[((size_t)j << 11) + ((c + j) & (U_ - 1))];
  for (int t0 = 0; t0 < T_; t0 += 16) {
    #pragma unroll
    for (int j = 0; j < 8; ++j) {
      const int t = t0 + 8 + j;
      wB[j] = base[((size_t)t << 11) + ((c + t) & (U_ - 1))];
    }
    #pragma unroll
    for (int j = 0; j < 8; ++j) {
      const int t = t0 + j;
      h = fast_tanh(fmaf(RHO_, h, wA[j]));
      base[((size_t)t << 11) + ((c + t) & (U_ - 1))] = h;
    }
    if (t0 + 16 < T_) {
      #pragma unroll
      for (int j = 0; j < 8; ++j) {
        const int t = t0 + 16 + j;
        wA[j] = base[((size_t)t << 11) + ((c + t) & (U_ - 1))];
      }
    }
    #pragma unroll
    for (int j = 0; j < 8; ++j) {
      const int t = t0 + 8 + j;
      h = fast_tanh(fmaf(RHO_, h, wB[j]));
      base[((size_t)t << 11) + ((c + t) & (U_ - 1))] = h;
    }
  }
}

__global__ __launch_bounds__(256, 4) void gemm_bias_kernel(
    const float* __restrict__ A, const float* __restrict__ W,
    const float* __restrict__ bias, float* __restrict__ out) {
  __shared__ float Asf[64][68];
  __shared__ float Bsf[64][64];
  const int tid = threadIdx.x;
  const int m0 = blockIdx.y << 6;
  const int n0 = blockIdx.x << 6;
  const int tx = tid & 15;
  const int ty = tid >> 4;
  float acc[4][4] = {};
  #pragma unroll
  for (int kb = 0; kb < 2; ++kb) {
    if (kb) __syncthreads();
    {
      const int c4 = tid & 15;
      const int r0 = tid >> 4;
      #pragma unroll
      for (int rr = 0; rr < 4; ++rr) {
        const int r = r0 + (rr << 4);
        const float4 v = *(const float4*)(A + (size_t)(m0 + r) * K_ + (kb << 6) + (c4 << 2));
        Asf[(c4 << 2) + 0][r] = v.x;
        Asf[(c4 << 2) + 1][r] = v.y;
        Asf[(c4 << 2) + 2][r] = v.z;
        Asf[(c4 << 2) + 3][r] = v.w;
      }
    }
    {
      const int c4 = tid & 15;
      const int r0 = tid >> 4;
      #pragma unroll
      for (int rr = 0; rr < 4; ++rr) {
        const int k = r0 + (rr << 4);
        *(float4*)&Bsf[k][c4 << 2] =
            *(const float4*)(W + (size_t)((kb << 6) + k) * U_ + n0 + (c4 << 2));
      }
    }
    __syncthreads();
    #pragma unroll 16
    for (int k = 0; k < 64; ++k) {
      const float4 a = *(const float4*)&Asf[k][ty << 2];
      const float4 b = *(const float4*)&Bsf[k][tx << 2];
      acc[0][0] = fmaf(a.x, b.x, acc[0][0]); acc[0][1] = fmaf(a.x, b.y, acc[0][1]);
      acc[0][2] = fmaf(a.x, b.z, acc[0][2]); acc[0][3] = fmaf(a.x, b.w, acc[0][3]);
      acc[1][0] = fmaf(a.y, b.x, acc[1][0]); acc[1][1] = fmaf(a.y, b.y, acc[1][1]);
      acc[1][2] = fmaf(a.y, b.z, acc[1][2]); acc[1][3] = fmaf(a.y, b.w, acc[1][3]);
      acc[2][0] = fmaf(a.z, b.x, acc[2][0]); acc[2][1] = fmaf(a.z, b.y, acc[2][1]);
      acc[2][2] = fmaf(a.z, b.z, acc[2][2]); acc[2][3] = fmaf(a.z, b.w, acc[2][3]);
      acc[3][0] = fmaf(a.w, b.x, acc[3][0]); acc[3][1] = fmaf(a.w, b.y, acc[3][1]);
      acc[3][2] = fmaf(a.w, b.z, acc[3][2]); acc[3][3] = fmaf(a.w, b.w, acc[3][3]);
    }
  }
  const float4 bv = *(const float4*)(bias + n0 + (tx << 2));
  #pragma unroll
  for (int i = 0; i < 4; ++i) {
    float4 o;
    o.x = acc[i][0] + bv.x; o.y = acc[i][1] + bv.y;
    o.z = acc[i][2] + bv.z; o.w = acc[i][3] + bv.w;
    *(float4*)(out + (size_t)(m0 + (ty << 2) + i) * U_ + n0 + (tx << 2)) = o;
  }
}

extern "C" void kernel_launch(void* const* d_in, const int* in_sizes, int n_in,
                              void* d_out, int out_size, void* d_ws, size_t ws_size,
                              hipStream_t stream) {
  const float* A    = (const float*)d_in[0];   // inputs [B,T,D_IN]
  const float* h0   = (const float*)d_in[1];   // [B,U]
  const float* W    = (const float*)d_in[2];   // kernel [D_IN,U]
  const float* bias = (const float*)d_in[3];   // [U]
  float* out = (float*)d_out;                  // [B,T,U]

  const size_t AB_BYTES = (size_t)B_ * T_ * 256 * 2;         // 8,388,608
  const size_t WB_BYTES = (size_t)U_ * 256 * 2;              // 1,048,576
  const size_t NEEDED = AB_BYTES + WB_BYTES;

  if (ws_size >= NEEDED) {
    unsigned short* Ab  = (unsigned short*)d_ws;
    unsigned short* Wbt = (unsigned short*)((char*)d_ws + AB_BYTES);

    convert_a_kernel<<<2048, 256, 0, stream>>>(A, Ab);
    convert_w_kernel<<<256, 256, 0, stream>>>(W, Wbt);
    dim3 fg(U_ / 256, B_);              // (8, 32) = 256 blocks
    fused_gemm_scan_kernel<<<fg, 256, 0, stream>>>(Ab, Wbt, bias, h0, out);
  } else {
    dim3 gemm_grid(U_ / 64, (B_ * T_) / 64);
    gemm_bias_kernel<<<gemm_grid, 256, 0, stream>>>(A, W, bias, out);
    dim3 scan_grid(U_ / 256, B_);       // (8, 32)
    ring_scan_kernel<<<scan_grid, 256, 0, stream>>>(out, h0);
  }
}

// Round 6
// 221.700 us; speedup vs baseline: 1.1940x; 1.1658x over previous
//
#include <hip/hip_runtime.h>
#include <hip/hip_bf16.h>

#define U_ 2048
#define T_ 512
#define K_ 128
#define B_ 32
#define RHO_ 0.99f
#define CPB 128      // chains per block
#define NTILES 9     // 16-col tiles covering 128+15 cols
#define NSLOTS 10    // W ring slots (1 spare for prefetch)

typedef __attribute__((ext_vector_type(8))) short short8;
typedef __attribute__((ext_vector_type(4))) float f32x4;

__device__ __forceinline__ float fast_tanh(float x) {
  float e = __expf(2.0f * x);          // inf for large x -> returns +/-1 correctly
  return 1.0f - 2.0f / (e + 1.0f);
}

__device__ __forceinline__ unsigned short bf16_rne(float x) {
  unsigned int u = __float_as_uint(x);
  u += 0x7FFFu + ((u >> 16) & 1u);
  return (unsigned short)(u >> 16);
}

// ---------------- converts ----------------
// A [16384][128] fp32 -> Ab [16384][256] bf16 (k<128: hi, k>=128: lo residual)
__global__ __launch_bounds__(256) void convert_a_kernel(
    const float* __restrict__ A, unsigned short* __restrict__ Ab) {
  const int gi = blockIdx.x * 256 + threadIdx.x;
  const int m = gi >> 5;          // needs 2048 blocks
  const int kq = (gi & 31) << 2;
  const float4 v = *(const float4*)&A[(size_t)m * K_ + kq];
  ushort4 hi, lo;
  hi.x = bf16_rne(v.x); hi.y = bf16_rne(v.y); hi.z = bf16_rne(v.z); hi.w = bf16_rne(v.w);
  lo.x = bf16_rne(v.x - __uint_as_float((unsigned)hi.x << 16));
  lo.y = bf16_rne(v.y - __uint_as_float((unsigned)hi.y << 16));
  lo.z = bf16_rne(v.z - __uint_as_float((unsigned)hi.z << 16));
  lo.w = bf16_rne(v.w - __uint_as_float((unsigned)hi.w << 16));
  *(ushort4*)&Ab[(size_t)m * 256 + kq] = hi;
  *(ushort4*)&Ab[(size_t)m * 256 + 128 + kq] = lo;
}

// W [128][2048] fp32 -> Wbt [2048][256] bf16 transposed, duplicated along k.
__global__ __launch_bounds__(256) void convert_w_kernel(
    const float* __restrict__ W, unsigned short* __restrict__ Wbt) {
  const int gi = blockIdx.x * 256 + threadIdx.x;   // 65536 threads
  const int kq = gi >> 11;        // 0..31
  const int n = gi & 2047;
  const int k = kq << 2;
  ushort4 w;
  w.x = bf16_rne(W[(size_t)(k + 0) * U_ + n]);
  w.y = bf16_rne(W[(size_t)(k + 1) * U_ + n]);
  w.z = bf16_rne(W[(size_t)(k + 2) * U_ + n]);
  w.w = bf16_rne(W[(size_t)(k + 3) * U_ + n]);
  *(ushort4*)&Wbt[(size_t)n * 256 + k] = w;
  *(ushort4*)&Wbt[(size_t)n * 256 + 128 + k] = w;
}

// ---------------- v8: fused GEMM+scan, W-LDS ring, 2 blocks/CU ----------------
// Block = 128 chains of one batch.  Per 16-step t-tile:
//   MFMA u-tile [16 x 144] from af regs (A hi/lo) x W ring in LDS -> u_lds
//   -> 16 serial tanh steps on the diagonal (tid<128), nt-store h to out.
// W ring: 10 slots x [16n x 128k] bf16 (4KB), granule-XOR swizzle
// (write granule = g ^ (n&7); read applies same XOR) -> 8-pass-optimal b128.
// Only 4KB fresh W per iter (window slides 16 cols).  B-frags via ds_read
// kill v7's 80-VGPR bf array -> no scratch spill.  512 blocks, 57KB LDS
// -> 2 blocks/CU: one block's serial scan overlaps the other's MFMA/loads.
// XCD swizzle: each XCD owns 4 whole batches -> Ab panels L2-resident.
__global__ __launch_bounds__(256, 2) void fused_gemm_scan2_kernel(
    const unsigned short* __restrict__ Ab, const unsigned short* __restrict__ Wbt,
    const float* __restrict__ bias, const float* __restrict__ h0,
    float* __restrict__ out) {
  __shared__ unsigned short Wl[NSLOTS * 2048];   // 40 KB
  __shared__ float u_lds[16 * 146];              // 9344 B
  __shared__ float bias_lds[U_];                 // 8 KB
  const int tid = threadIdx.x;
  // XCD-aware remap: linear id -> (batch, chain-group) so each XCD (id&7)
  // owns 4 full batches -> its L2 holds those Ab panels + Wbt.
  const int id = blockIdx.x + (blockIdx.y << 4);   // 0..511
  const int xcd = id & 7;
  const int wk = id >> 3;                          // 0..63
  const int b = (xcd << 2) + (wk >> 4);            // batch 0..31
  const int bx = wk & 15;                          // chain group 0..15
  const int c0 = bx << 7;
  const int cbase = bx << 3;                       // col-tile base
  const int wave = tid >> 6;
  const int lane = tid & 63;
  const int r = lane & 15;
  const int q = lane >> 4;
  const int koff = q << 3;
  const int nloc = tid >> 4;                       // staging row 0..15
  const int gran = tid & 15;                       // staging granule
  const int sgran = gran ^ (nloc & 7);             // swizzled granule

  #pragma unroll
  for (int i = 0; i < 8; ++i)
    bias_lds[(i << 8) + tid] = bias[(i << 8) + tid];

  // prologue: stage W ring slots 0..8
  #pragma unroll
  for (int j = 0; j < NTILES; ++j) {
    const int g = (cbase + j) & 127;
    const short8 w0 = *(const short8*)(Wbt + ((((size_t)g << 4) + nloc) << 8) + (gran << 3));
    *(short8*)&Wl[(j << 11) + (nloc << 7) + (sgran << 3)] = w0;
  }

  const unsigned short* const aBase = Ab + (((size_t)b * T_) << 8);
  short8 af[8];
  #pragma unroll
  for (int ks = 0; ks < 8; ++ks)
    af[ks] = *(const short8*)(aBase + (((size_t)r) << 8) + (ks << 5) + koff);

  float h = 0.0f;
  if (tid < CPB)
    h = h0[((size_t)b << 11) + ((c0 + tid + U_ - 1) & (U_ - 1))];

  __syncthreads();                     // ring + bias ready

  for (int it = 0; it < T_ / 16; ++it) {
    const int t0 = it << 4;

    // early-issue next W col-tile (its slot is idle this whole iter);
    // latency hides under the MFMA phase.
    short8 wv;
    if (it + 1 < T_ / 16) {
      const int gnew = (cbase + it + NTILES) & 127;
      wv = *(const short8*)(Wbt + ((((size_t)gnew << 4) + nloc) << 8) + (gran << 3));
    }

    // ---- MFMA phase: wave w -> tiles {w, w+4} (+8 for wave 0) ----
    f32x4 acc[3];
    #pragma unroll
    for (int u = 0; u < 3; ++u) {
      acc[u] = (f32x4){0.f, 0.f, 0.f, 0.f};
      const int j = (u < 2) ? (wave + (u << 2)) : 8;
      if (u < 2 || wave == 0) {
        const int slot = (it + j) % NSLOTS;
        short8 bfk[4];
        #pragma unroll
        for (int ks = 0; ks < 4; ++ks)
          bfk[ks] = *(const short8*)&Wl[(slot << 11) + (r << 7) +
                                        ((((ks << 2) + q) ^ (r & 7)) << 3)];
        #pragma unroll
        for (int ks = 0; ks < 8; ++ks)   // lo-half reuses same W (dup'd k)
          acc[u] = __builtin_amdgcn_mfma_f32_16x16x32_bf16(af[ks], bfk[ks & 3], acc[u], 0, 0, 0);
      }
    }

    __syncthreads();                   // prev scan's u_lds reads retired

    // ---- u + bias -> LDS (D layout: col=lane&15, row=q*4+reg) ----
    #pragma unroll
    for (int u = 0; u < 3; ++u) {
      const int j = (u < 2) ? (wave + (u << 2)) : 8;
      if (u < 2 || wave == 0) {
        const float bv = bias_lds[(c0 + t0 + (j << 4) + r) & (U_ - 1)];
        #pragma unroll
        for (int reg = 0; reg < 4; ++reg)
          u_lds[((q << 2) + reg) * 146 + (j << 4) + r] = acc[u][reg] + bv;
      }
    }

    // ---- prefetch next-iter A frags (covered by scan); commit W tile ----
    if (it + 1 < T_ / 16) {
      #pragma unroll
      for (int ks = 0; ks < 8; ++ks)
        af[ks] = *(const short8*)(aBase + (((size_t)(t0 + 16 + r)) << 8) + (ks << 5) + koff);
      const int snew = (it + NTILES) % NSLOTS;
      *(short8*)&Wl[(snew << 11) + (nloc << 7) + (sgran << 3)] = wv;
    }

    __syncthreads();                   // u_lds + ring write visible

    // ---- scan: 16 sequential steps on the diagonal (waves 0-1) ----
    if (tid < CPB) {
      float uv[16];
      #pragma unroll
      for (int tt = 0; tt < 16; ++tt)
        uv[tt] = u_lds[tt * 146 + tid + tt];
      float* const orow = out + (((size_t)(b * T_ + t0)) << 11);
      #pragma unroll
      for (int tt = 0; tt < 16; ++tt) {
        h = fast_tanh(fmaf(RHO_, h, uv[tt]));
        __builtin_nontemporal_store(
            h, &orow[((size_t)tt << 11) + ((c0 + tid + t0 + tt) & (U_ - 1))]);
      }
    }
    // waves 2-3 legally run ahead into next iter's MFMA phase (reads only
    // Wl/af, no conflict with the scan's u_lds reads), then wait at barrier1.
  }
}

// ---------------- fallback path (R1, proven correct) ----------------
__global__ __launch_bounds__(256) void ring_scan_kernel(
    float* __restrict__ buf, const float* __restrict__ h0) {
  const int b = blockIdx.y;
  const int c = (blockIdx.x << 8) + threadIdx.x;
  float* const base = buf + (size_t)b * (T_ * U_);
  float h = h0[((size_t)b << 11) + ((c + U_ - 1) & (U_ - 1))];
  float wA[8], wB[8];
  #pragma unroll
  for (int j = 0; j < 8; ++j)
    wA[j] = base[((size_t)j << 11) + ((c + j) & (U_ - 1))];
  for (int t0 = 0; t0 < T_; t0 += 16) {
    #pragma unroll
    for (int j = 0; j < 8; ++j) {
      const int t = t0 + 8 + j;
      wB[j] = base[((size_t)t << 11) + ((c + t) & (U_ - 1))];
    }
    #pragma unroll
    for (int j = 0; j < 8; ++j) {
      const int t = t0 + j;
      h = fast_tanh(fmaf(RHO_, h, wA[j]));
      base[((size_t)t << 11) + ((c + t) & (U_ - 1))] = h;
    }
    if (t0 + 16 < T_) {
      #pragma unroll
      for (int j = 0; j < 8; ++j) {
        const int t = t0 + 16 + j;
        wA[j] = base[((size_t)t << 11) + ((c + t) & (U_ - 1))];
      }
    }
    #pragma unroll
    for (int j = 0; j < 8; ++j) {
      const int t = t0 + 8 + j;
      h = fast_tanh(fmaf(RHO_, h, wB[j]));
      base[((size_t)t << 11) + ((c + t) & (U_ - 1))] = h;
    }
  }
}

__global__ __launch_bounds__(256, 4) void gemm_bias_kernel(
    const float* __restrict__ A, const float* __restrict__ W,
    const float* __restrict__ bias, float* __restrict__ out) {
  __shared__ float Asf[64][68];
  __shared__ float Bsf[64][64];
  const int tid = threadIdx.x;
  const int m0 = blockIdx.y << 6;
  const int n0 = blockIdx.x << 6;
  const int tx = tid & 15;
  const int ty = tid >> 4;
  float acc[4][4] = {};
  #pragma unroll
  for (int kb = 0; kb < 2; ++kb) {
    if (kb) __syncthreads();
    {
      const int c4 = tid & 15;
      const int r0 = tid >> 4;
      #pragma unroll
      for (int rr = 0; rr < 4; ++rr) {
        const int r = r0 + (rr << 4);
        const float4 v = *(const float4*)(A + (size_t)(m0 + r) * K_ + (kb << 6) + (c4 << 2));
        Asf[(c4 << 2) + 0][r] = v.x;
        Asf[(c4 << 2) + 1][r] = v.y;
        Asf[(c4 << 2) + 2][r] = v.z;
        Asf[(c4 << 2) + 3][r] = v.w;
      }
    }
    {
      const int c4 = tid & 15;
      const int r0 = tid >> 4;
      #pragma unroll
      for (int rr = 0; rr < 4; ++rr) {
        const int k = r0 + (rr << 4);
        *(float4*)&Bsf[k][c4 << 2] =
            *(const float4*)(W + (size_t)((kb << 6) + k) * U_ + n0 + (c4 << 2));
      }
    }
    __syncthreads();
    #pragma unroll 16
    for (int k = 0; k < 64; ++k) {
      const float4 a = *(const float4*)&Asf[k][ty << 2];
      const float4 b = *(const float4*)&Bsf[k][tx << 2];
      acc[0][0] = fmaf(a.x, b.x, acc[0][0]); acc[0][1] = fmaf(a.x, b.y, acc[0][1]);
      acc[0][2] = fmaf(a.x, b.z, acc[0][2]); acc[0][3] = fmaf(a.x, b.w, acc[0][3]);
      acc[1][0] = fmaf(a.y, b.x, acc[1][0]); acc[1][1] = fmaf(a.y, b.y, acc[1][1]);
      acc[1][2] = fmaf(a.y, b.z, acc[1][2]); acc[1][3] = fmaf(a.y, b.w, acc[1][3]);
      acc[2][0] = fmaf(a.z, b.x, acc[2][0]); acc[2][1] = fmaf(a.z, b.y, acc[2][1]);
      acc[2][2] = fmaf(a.z, b.z, acc[2][2]); acc[2][3] = fmaf(a.z, b.w, acc[2][3]);
      acc[3][0] = fmaf(a.w, b.x, acc[3][0]); acc[3][1] = fmaf(a.w, b.y, acc[3][1]);
      acc[3][2] = fmaf(a.w, b.z, acc[3][2]); acc[3][3] = fmaf(a.w, b.w, acc[3][3]);
    }
  }
  const float4 bv = *(const float4*)(bias + n0 + (tx << 2));
  #pragma unroll
  for (int i = 0; i < 4; ++i) {
    float4 o;
    o.x = acc[i][0] + bv.x; o.y = acc[i][1] + bv.y;
    o.z = acc[i][2] + bv.z; o.w = acc[i][3] + bv.w;
    *(float4*)(out + (size_t)(m0 + (ty << 2) + i) * U_ + n0 + (tx << 2)) = o;
  }
}

extern "C" void kernel_launch(void* const* d_in, const int* in_sizes, int n_in,
                              void* d_out, int out_size, void* d_ws, size_t ws_size,
                              hipStream_t stream) {
  const float* A    = (const float*)d_in[0];   // inputs [B,T,D_IN]
  const float* h0   = (const float*)d_in[1];   // [B,U]
  const float* W    = (const float*)d_in[2];   // kernel [D_IN,U]
  const float* bias = (const float*)d_in[3];   // [U]
  float* out = (float*)d_out;                  // [B,T,U]

  const size_t AB_BYTES = (size_t)B_ * T_ * 256 * 2;         // 8,388,608
  const size_t WB_BYTES = (size_t)U_ * 256 * 2;              // 1,048,576
  const size_t NEEDED = AB_BYTES + WB_BYTES;

  if (ws_size >= NEEDED) {
    unsigned short* Ab  = (unsigned short*)d_ws;
    unsigned short* Wbt = (unsigned short*)((char*)d_ws + AB_BYTES);

    convert_a_kernel<<<2048, 256, 0, stream>>>(A, Ab);
    convert_w_kernel<<<256, 256, 0, stream>>>(W, Wbt);
    dim3 fg(U_ / CPB, B_);              // (16, 32) = 512 blocks
    fused_gemm_scan2_kernel<<<fg, 256, 0, stream>>>(Ab, Wbt, bias, h0, out);
  } else {
    dim3 gemm_grid(U_ / 64, (B_ * T_) / 64);
    gemm_bias_kernel<<<gemm_grid, 64, 0, stream>>>(A, W, bias, out);
    dim3 scan_grid(U_ / 256, B_);       // (8, 32)
    ring_scan_kernel<<<scan_grid, 256, 0, stream>>>(out, h0);
  }
}